// Round 1
// baseline (188.516 us; speedup 1.0000x reference)
//
#include <hip/hip_runtime.h>
#include <math.h>

#define LEAK 0.2f

__device__ __forceinline__ float leaky_f(float x) { return x >= 0.0f ? x : LEAK * x; }
__device__ __forceinline__ float sigmoid_f(float x) { return 1.0f / (1.0f + expf(-x)); }

// One block per batch element (B=32), 128 threads (thread j owns hidden unit j).
// Only timesteps t=0,1,2 are needed: the reference's output is out[:, 2:3, :].
__global__ __launch_bounds__(128)
void lstm_cls_kernel(const float* __restrict__ data,
                     const float* __restrict__ W_M1, const float* __restrict__ b_M1,
                     const float* __restrict__ W_M2, const float* __restrict__ b_M2,
                     const float* __restrict__ W_T1, const float* __restrict__ b_T1,
                     const float* __restrict__ W_T2, const float* __restrict__ b_T2,
                     const float* __restrict__ W_S1, const float* __restrict__ b_S1,
                     const float* __restrict__ W_S2, const float* __restrict__ b_S2,
                     const float* __restrict__ Wk,   const float* __restrict__ b_l,
                     const float* __restrict__ Wr,
                     const float* __restrict__ W_P1, const float* __restrict__ b_P1,
                     const float* __restrict__ W_P2, const float* __restrict__ b_P2,
                     const float* __restrict__ W_P3, const float* __restrict__ b_P3,
                     const float* __restrict__ W_P4, const float* __restrict__ b_P4,
                     const float* __restrict__ W_P5, const float* __restrict__ b_P5,
                     float* __restrict__ out)
{
    __shared__ float sdata[3][11];   // data[b, t, :] for t=0..2
    __shared__ float feat[3][124];   // lstm_in: [M(16) Tsk(16) Psk(16) Pa(1) S(64) data(11)]
    __shared__ float m1s[3][8];
    __shared__ float t1s[3][8];
    __shared__ float s1s[3][32];
    __shared__ float zx[3][512];
    __shared__ float h[128];
    __shared__ float d1[64], d2[32], d3[16], d4[8];
    __shared__ float sm[3];

    const int b   = blockIdx.x;
    const int tid = threadIdx.x;
    const float* db = data + (size_t)b * 4096 * 11;

    // ---- load data[b, 0:3, :] (33 floats) ----
    if (tid < 33) {
        int t = tid / 11, k = tid % 11;
        float v = db[t * 11 + k];
        sdata[t][k] = v;
        feat[t][113 + k] = v;          // lstm_in tail = raw data
    }
    __syncthreads();

    // ---- stage B: m1 = leaky(body @ W_M1 + b) [24], t1 = |leaky(data @ W_T1 + b)| [24], Pa [3] ----
    if (tid < 24) {
        int t = tid / 8, j = tid % 8;
        float acc = b_M1[j];
        for (int k = 0; k < 6; ++k) acc += sdata[t][4 + k] * W_M1[k * 8 + j];
        m1s[t][j] = leaky_f(acc);
    } else if (tid < 48) {
        int u = tid - 24, t = u / 8, j = u % 8;
        float acc = b_T1[j];
        for (int k = 0; k < 11; ++k) acc += sdata[t][k] * W_T1[k * 8 + j];
        t1s[t][j] = fabsf(leaky_f(acc));
    } else if (tid < 51) {
        int t = tid - 48;
        feat[t][48] = log1pf(sdata[t][1]);   // Pa = log1p(Ta)
    }
    __syncthreads();

    // ---- stage C: M [48], Tsk + Psk [48] ----
    if (tid < 48) {
        int t = tid / 16, j = tid % 16;
        float acc = b_M2[j];
        for (int k = 0; k < 8; ++k) acc += m1s[t][k] * W_M2[k * 16 + j];
        feat[t][j] = leaky_f(acc);                 // M
    } else if (tid < 96) {
        int u = tid - 48, t = u / 16, j = u % 16;
        float acc = b_T2[j];
        for (int k = 0; k < 8; ++k) acc += t1s[t][k] * W_T2[k * 16 + j];
        float v = fabsf(leaky_f(acc));
        feat[t][16 + j] = v;                       // Tsk
        feat[t][32 + j] = log1pf(v);               // Psk
    }
    __syncthreads();

    // ---- stage D: s1 = leaky(s_in @ W_S1 + b)  (s_in = [M Tsk Psk Pa | env | body], 58) ----
    if (tid < 96) {
        int t = tid / 32, j = tid % 32;
        float acc = b_S1[j];
        for (int k = 0; k < 49; ++k) acc += feat[t][k] * W_S1[k * 32 + j];
        for (int k = 0; k < 3;  ++k) acc += sdata[t][1 + k] * W_S1[(49 + k) * 32 + j]; // env
        for (int k = 0; k < 6;  ++k) acc += sdata[t][4 + k] * W_S1[(52 + k) * 32 + j]; // body
        s1s[t][j] = leaky_f(acc);
    }
    __syncthreads();

    // ---- stage E: S = leaky(s1 @ W_S2 + b) [192 tasks] ----
    for (int idx = tid; idx < 192; idx += 128) {
        int t = idx / 64, j = idx % 64;
        float acc = b_S2[j];
        for (int k = 0; k < 32; ++k) acc += s1s[t][k] * W_S2[k * 64 + j];
        feat[t][49 + j] = leaky_f(acc);
    }
    __syncthreads();

    // ---- stage F: zx[t] = feat[t] @ Wk + b_l  [1536 tasks, coalesced on col] ----
    for (int idx = tid; idx < 1536; idx += 128) {
        int t = idx / 512, col = idx % 512;
        float acc = b_l[col];
        for (int k = 0; k < 124; ++k) acc += feat[t][k] * Wk[k * 512 + col];
        zx[t][col] = acc;
    }
    h[tid] = 0.0f;
    float c = 0.0f;
    __syncthreads();

    // ---- LSTM: 3 steps, thread j owns hidden unit j ----
    const int j = tid;
    for (int t = 0; t < 3; ++t) {
        float zi = zx[t][j];
        float zf = zx[t][128 + j];
        float zg = zx[t][256 + j];
        float zo = zx[t][384 + j];
        if (t > 0) {
            for (int k = 0; k < 128; ++k) {
                float hk = h[k];
                const float* wrow = Wr + (size_t)k * 512;
                zi += hk * wrow[j];
                zf += hk * wrow[128 + j];
                zg += hk * wrow[256 + j];
                zo += hk * wrow[384 + j];
            }
        }
        c = sigmoid_f(zf) * c + sigmoid_f(zi) * leaky_f(zg);
        float hn = sigmoid_f(zo) * leaky_f(c);
        __syncthreads();
        h[j] = hn;
        __syncthreads();
    }

    // ---- head: 128 -> 64 -> 32 -> 16 -> 8 -> 3, softmax ----
    if (tid < 64) {
        float acc = b_P1[tid];
        for (int k = 0; k < 128; ++k) acc += h[k] * W_P1[k * 64 + tid];
        d1[tid] = leaky_f(acc);
    }
    __syncthreads();
    if (tid < 32) {
        float acc = b_P2[tid];
        for (int k = 0; k < 64; ++k) acc += d1[k] * W_P2[k * 32 + tid];
        d2[tid] = leaky_f(acc);
    }
    __syncthreads();
    if (tid < 16) {
        float acc = b_P3[tid];
        for (int k = 0; k < 32; ++k) acc += d2[k] * W_P3[k * 16 + tid];
        d3[tid] = leaky_f(acc);
    }
    __syncthreads();
    if (tid < 8) {
        float acc = b_P4[tid];
        for (int k = 0; k < 16; ++k) acc += d3[k] * W_P4[k * 8 + tid];
        d4[tid] = leaky_f(acc);
    }
    __syncthreads();
    if (tid == 0) {
        float l[3], mx = -1e30f;
        for (int r = 0; r < 3; ++r) {
            float acc = b_P5[r];
            for (int k = 0; k < 8; ++k) acc += d4[k] * W_P5[k * 3 + r];
            l[r] = leaky_f(acc);
            mx = fmaxf(mx, l[r]);
        }
        float s = 0.0f;
        for (int r = 0; r < 3; ++r) { l[r] = expf(l[r] - mx); s += l[r]; }
        float inv = 1.0f / s;
        for (int r = 0; r < 3; ++r) sm[r] = l[r] * inv;
    }
    __syncthreads();

    // ---- outputs: d_out[0:96] = softmax(t=2), d_out[96:512] = concat(data[b,2,1:11], softmax) ----
    if (tid < 3)  out[b * 3 + tid] = sm[tid];
    if (tid < 13) {
        float v = (tid < 10) ? sdata[2][1 + tid] : sm[tid - 10];
        out[96 + b * 13 + tid] = v;
    }
}

extern "C" void kernel_launch(void* const* d_in, const int* in_sizes, int n_in,
                              void* d_out, int out_size, void* d_ws, size_t ws_size,
                              hipStream_t stream) {
    const float* data = (const float*)d_in[0];
    const float* W_M1 = (const float*)d_in[1];
    const float* b_M1 = (const float*)d_in[2];
    const float* W_M2 = (const float*)d_in[3];
    const float* b_M2 = (const float*)d_in[4];
    const float* W_T1 = (const float*)d_in[5];
    const float* b_T1 = (const float*)d_in[6];
    const float* W_T2 = (const float*)d_in[7];
    const float* b_T2 = (const float*)d_in[8];
    const float* W_S1 = (const float*)d_in[9];
    const float* b_S1 = (const float*)d_in[10];
    const float* W_S2 = (const float*)d_in[11];
    const float* b_S2 = (const float*)d_in[12];
    const float* Wk   = (const float*)d_in[13];
    const float* Wr   = (const float*)d_in[14];
    const float* b_l  = (const float*)d_in[15];
    const float* W_P1 = (const float*)d_in[16];
    const float* b_P1 = (const float*)d_in[17];
    const float* W_P2 = (const float*)d_in[18];
    const float* b_P2 = (const float*)d_in[19];
    const float* W_P3 = (const float*)d_in[20];
    const float* b_P3 = (const float*)d_in[21];
    const float* W_P4 = (const float*)d_in[22];
    const float* b_P4 = (const float*)d_in[23];
    const float* W_P5 = (const float*)d_in[24];
    const float* b_P5 = (const float*)d_in[25];
    float* out = (float*)d_out;

    lstm_cls_kernel<<<dim3(32), dim3(128), 0, stream>>>(
        data, W_M1, b_M1, W_M2, b_M2, W_T1, b_T1, W_T2, b_T2,
        W_S1, b_S1, W_S2, b_S2, Wk, b_l, Wr,
        W_P1, b_P1, W_P2, b_P2, W_P3, b_P3, W_P4, b_P4, W_P5, b_P5,
        out);
}

// Round 2
// 129.566 us; speedup vs baseline: 1.4550x; 1.4550x over previous
//
#include <hip/hip_runtime.h>
#include <math.h>

#define LEAK 0.2f

__device__ __forceinline__ float leaky_f(float x) { return x >= 0.0f ? x : LEAK * x; }
__device__ __forceinline__ float sigmoid_f(float x) { return 1.0f / (1.0f + expf(-x)); }

// One block per batch element (B=32), 512 threads.
// Only timesteps t=0,1,2 matter: the reference output is out[:, 2:3, :].
// 512 threads = 8 waves/CU for memory-level parallelism; bulk-prefetch of
// Wr/W_P1/W_P2 at kernel start converts serialized per-stage HBM latency
// into one parallel burst that warms L2 before the serial LSTM steps.
__global__ __launch_bounds__(512)
void lstm_cls_kernel(const float* __restrict__ data,
                     const float* __restrict__ W_M1, const float* __restrict__ b_M1,
                     const float* __restrict__ W_M2, const float* __restrict__ b_M2,
                     const float* __restrict__ W_T1, const float* __restrict__ b_T1,
                     const float* __restrict__ W_T2, const float* __restrict__ b_T2,
                     const float* __restrict__ W_S1, const float* __restrict__ b_S1,
                     const float* __restrict__ W_S2, const float* __restrict__ b_S2,
                     const float* __restrict__ Wk,   const float* __restrict__ b_l,
                     const float* __restrict__ Wr,
                     const float* __restrict__ W_P1, const float* __restrict__ b_P1,
                     const float* __restrict__ W_P2, const float* __restrict__ b_P2,
                     const float* __restrict__ W_P3, const float* __restrict__ b_P3,
                     const float* __restrict__ W_P4, const float* __restrict__ b_P4,
                     const float* __restrict__ W_P5, const float* __restrict__ b_P5,
                     float* __restrict__ out)
{
    __shared__ float sdata[3][11];   // data[b, t, :] for t=0..2
    __shared__ float feat[3][124];   // lstm_in: [M(16) Tsk(16) Psk(16) Pa(1) S(64) data(11)]
    __shared__ float m1s[3][8];
    __shared__ float t1s[3][8];
    __shared__ float s1s[3][32];
    __shared__ float zx[3][512];
    __shared__ float zs[4][128];
    __shared__ float h[128];
    __shared__ float pp[8][64];      // split-K partials for head layers
    __shared__ float d1[64], d2[32], d3[16], d4[8];
    __shared__ float sm[3];

    const int b   = blockIdx.x;
    const int tid = threadIdx.x;
    const float* db = data + (size_t)b * 4096 * 11;

    // ---- load data[b, 0:3, :] (33 floats) ----
    if (tid < 33) {
        int t = tid / 11, k = tid % 11;
        float v = db[t * 11 + k];
        sdata[t][k] = v;
        feat[t][113 + k] = v;          // lstm_in tail = raw data
    }

    // ---- bulk prefetch: Wr (256KB) + W_P1 (32KB) + W_P2 (8KB) ----
    // Issued before the dependent stages so the fetch is one parallel burst.
    float pf = 0.0f;
    #pragma unroll 16
    for (int i = 0; i < 128; ++i) pf += Wr[i * 512 + tid];
    #pragma unroll
    for (int i = 0; i < 16; ++i)  pf += W_P1[i * 512 + tid];
    #pragma unroll
    for (int i = 0; i < 4; ++i)   pf += W_P2[i * 512 + tid];

    __syncthreads();

    // ---- stage B: m1 [24 tasks], t1 [24], Pa [3] ----
    if (tid < 24) {
        int t = tid / 8, j = tid % 8;
        float acc = b_M1[j];
        for (int k = 0; k < 6; ++k) acc += sdata[t][4 + k] * W_M1[k * 8 + j];
        m1s[t][j] = leaky_f(acc);
    } else if (tid < 48) {
        int u = tid - 24, t = u / 8, j = u % 8;
        float acc = b_T1[j];
        for (int k = 0; k < 11; ++k) acc += sdata[t][k] * W_T1[k * 8 + j];
        t1s[t][j] = fabsf(leaky_f(acc));
    } else if (tid < 51) {
        int t = tid - 48;
        feat[t][48] = log1pf(sdata[t][1]);   // Pa = log1p(Ta)
    }
    __syncthreads();

    // ---- stage C: M [48], Tsk + Psk [48] ----
    if (tid < 48) {
        int t = tid / 16, j = tid % 16;
        float acc = b_M2[j];
        for (int k = 0; k < 8; ++k) acc += m1s[t][k] * W_M2[k * 16 + j];
        feat[t][j] = leaky_f(acc);                 // M
    } else if (tid < 96) {
        int u = tid - 48, t = u / 16, j = u % 16;
        float acc = b_T2[j];
        for (int k = 0; k < 8; ++k) acc += t1s[t][k] * W_T2[k * 16 + j];
        float v = fabsf(leaky_f(acc));
        feat[t][16 + j] = v;                       // Tsk
        feat[t][32 + j] = log1pf(v);               // Psk
    }
    __syncthreads();

    // ---- stage D: s1 = leaky(s_in @ W_S1 + b), s_in = [feat[0:49] env body] ----
    if (tid < 96) {
        int t = tid / 32, j = tid % 32;
        float acc = b_S1[j];
        for (int k = 0; k < 49; ++k) acc += feat[t][k] * W_S1[k * 32 + j];
        for (int k = 0; k < 3;  ++k) acc += sdata[t][1 + k] * W_S1[(49 + k) * 32 + j]; // env
        for (int k = 0; k < 6;  ++k) acc += sdata[t][4 + k] * W_S1[(52 + k) * 32 + j]; // body
        s1s[t][j] = leaky_f(acc);
    }
    __syncthreads();

    // ---- stage E: S = leaky(s1 @ W_S2 + b) [192 tasks] ----
    if (tid < 192) {
        int t = tid / 64, j = tid % 64;
        float acc = b_S2[j];
        for (int k = 0; k < 32; ++k) acc += s1s[t][k] * W_S2[k * 64 + j];
        feat[t][49 + j] = leaky_f(acc);
    }
    __syncthreads();

    // ---- stage F: zx[t][col] for col=tid; one Wk load feeds all 3 timesteps ----
    {
        const int col = tid;
        float a0 = b_l[col], a1 = a0, a2 = a0;
        #pragma unroll 4
        for (int k = 0; k < 124; ++k) {
            float w = Wk[k * 512 + col];
            a0 += feat[0][k] * w;
            a1 += feat[1][k] * w;
            a2 += feat[2][k] * w;
        }
        zx[0][col] = a0; zx[1][col] = a1; zx[2][col] = a2;
    }
    if (tid < 128) h[tid] = 0.0f;
    float c = 0.0f;                    // live only for tid < 128
    const int g = tid >> 7, j = tid & 127;
    __syncthreads();

    // ---- LSTM: 3 steps, gate-parallel (thread (g,j) computes z[g*128+j]) ----
    for (int t = 0; t < 3; ++t) {
        float z = zx[t][(g << 7) + j];
        if (t > 0) {
            #pragma unroll 8
            for (int k = 0; k < 128; ++k)
                z += h[k] * Wr[k * 512 + (g << 7) + j];   // coalesced: tid-consecutive
        }
        zs[g][j] = z;
        __syncthreads();
        if (g == 0) {
            float zi = zs[0][j], zf = zs[1][j], zg = zs[2][j], zo = zs[3][j];
            c = sigmoid_f(zf) * c + sigmoid_f(zi) * leaky_f(zg);
            h[j] = sigmoid_f(zo) * leaky_f(c);
        }
        __syncthreads();
    }

    // ---- head: 128 -> 64 (split-K 8x16) ----
    {
        int part = tid >> 6, jj = tid & 63;
        float acc = 0.0f;
        for (int k = part * 16; k < part * 16 + 16; ++k)
            acc += h[k] * W_P1[k * 64 + jj];
        pp[part][jj] = acc;
    }
    __syncthreads();
    if (tid < 64) {
        float acc = b_P1[tid];
        for (int p = 0; p < 8; ++p) acc += pp[p][tid];
        d1[tid] = leaky_f(acc);
    }
    __syncthreads();

    // ---- 64 -> 32 (split-K 8x8) ----
    if (tid < 256) {
        int part = tid >> 5, jj = tid & 31;
        float acc = 0.0f;
        for (int k = part * 8; k < part * 8 + 8; ++k)
            acc += d1[k] * W_P2[k * 32 + jj];
        pp[part][jj] = acc;
    }
    __syncthreads();
    if (tid < 32) {
        float acc = b_P2[tid];
        for (int p = 0; p < 8; ++p) acc += pp[p][tid];
        d2[tid] = leaky_f(acc);
    }
    __syncthreads();

    // ---- 32 -> 16 (split-K 8x4) ----
    if (tid < 128) {
        int part = tid >> 4, jj = tid & 15;
        float acc = 0.0f;
        for (int k = part * 4; k < part * 4 + 4; ++k)
            acc += d2[k] * W_P3[k * 16 + jj];
        pp[part][jj] = acc;
    }
    __syncthreads();
    if (tid < 16) {
        float acc = b_P3[tid];
        for (int p = 0; p < 8; ++p) acc += pp[p][tid];
        d3[tid] = leaky_f(acc);
    }
    __syncthreads();

    // ---- 16 -> 8 ----
    if (tid < 8) {
        float acc = b_P4[tid];
        for (int k = 0; k < 16; ++k) acc += d3[k] * W_P4[k * 8 + tid];
        d4[tid] = leaky_f(acc);
    }
    __syncthreads();

    // ---- 8 -> 3 + softmax ----
    if (tid == 0) {
        float l[3], mx = -1e30f;
        for (int r = 0; r < 3; ++r) {
            float acc = b_P5[r];
            for (int k = 0; k < 8; ++k) acc += d4[k] * W_P5[k * 3 + r];
            l[r] = leaky_f(acc);
            mx = fmaxf(mx, l[r]);
        }
        float s = 0.0f;
        for (int r = 0; r < 3; ++r) { l[r] = expf(l[r] - mx); s += l[r]; }
        float inv = 1.0f / s;
        for (int r = 0; r < 3; ++r) sm[r] = l[r] * inv;
    }
    __syncthreads();

    // ---- outputs: d_out[0:96] = softmax(t=2); d_out[96:512] = concat(data[b,2,1:11], softmax) ----
    if (tid < 3)  out[b * 3 + tid] = sm[tid];
    if (tid < 13) {
        float v = (tid < 10) ? sdata[2][1 + tid] : sm[tid - 10];
        out[96 + b * 13 + tid] = v;
    }

    // keep the prefetch accumulator observable so the loads aren't dead-code
    // eliminated; condition is provably-false at runtime (data ~ U[0,1)).
    if (pf == -1234.5678f && sdata[2][0] == -99999.0f) out[0] = pf;
}

extern "C" void kernel_launch(void* const* d_in, const int* in_sizes, int n_in,
                              void* d_out, int out_size, void* d_ws, size_t ws_size,
                              hipStream_t stream) {
    const float* data = (const float*)d_in[0];
    const float* W_M1 = (const float*)d_in[1];
    const float* b_M1 = (const float*)d_in[2];
    const float* W_M2 = (const float*)d_in[3];
    const float* b_M2 = (const float*)d_in[4];
    const float* W_T1 = (const float*)d_in[5];
    const float* b_T1 = (const float*)d_in[6];
    const float* W_T2 = (const float*)d_in[7];
    const float* b_T2 = (const float*)d_in[8];
    const float* W_S1 = (const float*)d_in[9];
    const float* b_S1 = (const float*)d_in[10];
    const float* W_S2 = (const float*)d_in[11];
    const float* b_S2 = (const float*)d_in[12];
    const float* Wk   = (const float*)d_in[13];
    const float* Wr   = (const float*)d_in[14];
    const float* b_l  = (const float*)d_in[15];
    const float* W_P1 = (const float*)d_in[16];
    const float* b_P1 = (const float*)d_in[17];
    const float* W_P2 = (const float*)d_in[18];
    const float* b_P2 = (const float*)d_in[19];
    const float* W_P3 = (const float*)d_in[20];
    const float* b_P3 = (const float*)d_in[21];
    const float* W_P4 = (const float*)d_in[22];
    const float* b_P4 = (const float*)d_in[23];
    const float* W_P5 = (const float*)d_in[24];
    const float* b_P5 = (const float*)d_in[25];
    float* out = (float*)d_out;

    lstm_cls_kernel<<<dim3(32), dim3(512), 0, stream>>>(
        data, W_M1, b_M1, W_M2, b_M2, W_T1, b_T1, W_T2, b_T2,
        W_S1, b_S1, W_S2, b_S2, Wk, b_l, Wr,
        W_P1, b_P1, W_P2, b_P2, W_P3, b_P3, W_P4, b_P4, W_P5, b_P5,
        out);
}